// Round 10
// baseline (327.032 us; speedup 1.0000x reference)
//
#include <hip/hip_runtime.h>
#include <math.h>

// Problem constants
#define Bn    32
#define Tn    2000
#define Mrows (Bn * Tn)        // 64000
#define ENC2n 1024
#define ATTNn 512
#define DECn  512
#define NKn   10
#define KWn   100
#define PADn  50

// workspace layout (floats):
//   [0, 640000)            tmpconv [64000][10]
//   [OFF_DB, +16384)       DB[32][512] = b_enc + dec_e
//   [OFF_SCORE, +64000)    score [64000]
//   [OFF_WT, +262144)      Wt f16 [512 col][1024 k]  (transposed W_enc)
//   [OFF_AF16, +32768000)  Af16 [64000][1024]  (f16 copy of enc_output)
#define OFF_DB    (Mrows * NKn)
#define OFF_SCORE (OFF_DB + Bn * ATTNn)
#define OFF_WT    (OFF_SCORE + Mrows)
#define OFF_AF16  (OFF_WT + 262144)

typedef _Float16 v8h __attribute__((ext_vector_type(8)));
typedef float f32x4 __attribute__((ext_vector_type(4)));

__device__ __forceinline__ float fast_tanh(float v) {
  const float e = __expf(2.f * v);
  return 1.f - 2.f * __builtin_amdgcn_rcpf(e + 1.f);
}

__device__ __forceinline__ void gload_lds16(const void* g, void* l) {
  __builtin_amdgcn_global_load_lds(
      (const __attribute__((address_space(1))) void*)g,
      (__attribute__((address_space(3))) void*)l, 16, 0, 0);
}

// ---------------------------------------------------------------------------
// k_wt: W_enc [1024][512] f32 -> Wt [512][1024] f16 (transpose + convert, RNE)
// ---------------------------------------------------------------------------
__global__ __launch_bounds__(256) void k_wt(const float* __restrict__ W,
                                            _Float16* __restrict__ Wt) {
  __shared__ float sh[32][33];
  const int x = threadIdx.x & 31, y = threadIdx.x >> 5;  // y: 0..7
  const int k0 = blockIdx.x * 32, c0 = blockIdx.y * 32;
  for (int i = y; i < 32; i += 8) sh[i][x] = W[(size_t)(k0 + i) * ATTNn + c0 + x];
  __syncthreads();
  for (int i = y; i < 32; i += 8)
    Wt[(size_t)(c0 + i) * ENC2n + k0 + x] = (_Float16)sh[x][i];
}

// ---------------------------------------------------------------------------
// k_acvt: Af16 = (f16)enc_output, pure streaming (grid-stride)
// ---------------------------------------------------------------------------
__global__ __launch_bounds__(256) void k_acvt(const float* __restrict__ A,
                                              _Float16* __restrict__ Af) {
  const size_t total = (size_t)Mrows * ENC2n;
  const size_t stride = (size_t)gridDim.x * 256 * 8;
  for (size_t i = ((size_t)blockIdx.x * 256 + threadIdx.x) * 8; i < total;
       i += stride) {
    const float4 a = *(const float4*)(A + i);
    const float4 b = *(const float4*)(A + i + 4);
    v8h h;
    h[0] = (_Float16)a.x; h[1] = (_Float16)a.y;
    h[2] = (_Float16)a.z; h[3] = (_Float16)a.w;
    h[4] = (_Float16)b.x; h[5] = (_Float16)b.y;
    h[6] = (_Float16)b.z; h[7] = (_Float16)b.w;
    *(v8h*)(Af + i) = h;
  }
}

// ---------------------------------------------------------------------------
// k_conv: tmpconv[b,t,k] = sum_i alpha[b,t+i-50]*Wconv[k,i]; zero score acc
// ---------------------------------------------------------------------------
__global__ __launch_bounds__(256) void k_conv(const float* __restrict__ alpha,
                                              const float* __restrict__ Wconv,
                                              float* __restrict__ ws) {
  __shared__ float sh[256 + KWn - 1];
  __shared__ float wc[NKn * KWn];
  const int b = blockIdx.y;
  const int t0 = blockIdx.x * 256;
  const int tid = threadIdx.x;

  for (int i = tid; i < NKn * KWn; i += 256) wc[i] = Wconv[i];
  const float* __restrict__ arow = alpha + b * Tn;
  for (int i = tid; i < 256 + KWn - 1; i += 256) {
    const int t = t0 - PADn + i;
    sh[i] = (t >= 0 && t < Tn) ? arow[t] : 0.f;
  }
  __syncthreads();

  const int t = t0 + tid;
  if (t < Tn) {
    float acc[NKn];
#pragma unroll
    for (int k = 0; k < NKn; ++k) acc[k] = 0.f;
    for (int i = 0; i < KWn; ++i) {
      const float a = sh[tid + i];
#pragma unroll
      for (int k = 0; k < NKn; ++k) acc[k] = fmaf(a, wc[k * KWn + i], acc[k]);
    }
    float* tp = ws + (size_t)(b * Tn + t) * NKn;
#pragma unroll
    for (int k = 0; k < NKn; ++k) tp[k] = acc[k];
    ws[OFF_SCORE + b * Tn + t] = 0.f;
  }
}

// ---------------------------------------------------------------------------
// k_dec: DB[b,a] = b_enc[a] + sum_d h[b,d]*Wdec[d,a]
// ---------------------------------------------------------------------------
__global__ __launch_bounds__(512) void k_dec(const float* __restrict__ h,
                                             const float* __restrict__ Wdec,
                                             const float* __restrict__ benc,
                                             float* __restrict__ ws) {
  __shared__ float sh[DECn];
  const int b = blockIdx.x;
  const int a = threadIdx.x;
  sh[a] = h[b * DECn + a];
  __syncthreads();
  float acc = 0.f;
  for (int d = 0; d < DECn; ++d) acc = fmaf(sh[d], Wdec[d * ATTNn + a], acc);
  ws[OFF_DB + b * ATTNn + a] = benc[a] + acc;
}

#define BM 128
#define BN 128
#define BK 32
#define NT (ENC2n / BK)   // 32

// ---------------------------------------------------------------------------
// k_main: 128 threads / 2 waves; wave tile = 128 rows x 64 cols (af[8] x
// bf[4], 32 MFMA per wave-phase from 12 ds_read_b128 -> 1.78x better
// MFMA:LDS ratio than 64x64). Both operands DMA'd (global_load_lds, per-lane
// row-major source -> fragment-major LDS, linear dest). 3+3 buffers = 48 KB
// -> 3 blocks/CU for cross-block latency overlap. Phase t: issue W(t+2) then
// A(t+2); compute tile t; BARN(8) forces exactly tile t+1's 8 loads
// (in-order ledger). Tail: BARN(0) before tile 31.
// ---------------------------------------------------------------------------
#define DMAW(wb, kt) {                                                       \
  gload_lds16(aW0 + (kt) * BK, &Wb[wb][(4 * wv + 0) * 512]);                 \
  gload_lds16(aW1 + (kt) * BK, &Wb[wb][(4 * wv + 1) * 512]);                 \
  gload_lds16(aW2 + (kt) * BK, &Wb[wb][(4 * wv + 2) * 512]);                 \
  gload_lds16(aW3 + (kt) * BK, &Wb[wb][(4 * wv + 3) * 512]); }

#define DMAA(ab, kt) {                                                       \
  gload_lds16(aA0 + (kt) * BK, &Ab[ab][(4 * wv + 0) * 512]);                 \
  gload_lds16(aA1 + (kt) * BK, &Ab[ab][(4 * wv + 1) * 512]);                 \
  gload_lds16(aA2 + (kt) * BK, &Ab[ab][(4 * wv + 2) * 512]);                 \
  gload_lds16(aA3 + (kt) * BK, &Ab[ab][(4 * wv + 3) * 512]); }

#define COMPUTE(buf) {                                                       \
  v8h af[8], bf[4];                                                          \
  _Pragma("unroll")                                                          \
  for (int m = 0; m < 8; ++m)                                                \
    af[m] = *(const v8h*)&Ab[buf][m * 512 + lane * 8];                       \
  _Pragma("unroll")                                                          \
  for (int n = 0; n < 4; ++n)                                                \
    bf[n] = *(const v8h*)&Wb[buf][(4 * wv + n) * 512 + lane * 8];            \
  __builtin_amdgcn_s_setprio(1);                                             \
  _Pragma("unroll")                                                          \
  for (int m = 0; m < 8; ++m)                                                \
    _Pragma("unroll")                                                        \
    for (int n = 0; n < 4; ++n)                                              \
      acc[m][n] = __builtin_amdgcn_mfma_f32_16x16x32_f16(af[m], bf[n],       \
                                                         acc[m][n], 0, 0, 0);\
  __builtin_amdgcn_s_setprio(0); }

#define BARN(N) {                                                            \
  asm volatile("s_waitcnt vmcnt(" #N ") lgkmcnt(0)" ::: "memory");           \
  __builtin_amdgcn_s_barrier(); }

__global__ __launch_bounds__(128, 2) void k_main(
    const _Float16* __restrict__ Af,    // [64000][1024] f16
    const _Float16* __restrict__ Wt,    // [512][1024] f16
    const float* __restrict__ Wc2s,     // [10][512]
    const float* __restrict__ wscore,   // [512]
    float* __restrict__ ws) {
  __shared__ _Float16 Ab[3][4096];   // 24 KB
  __shared__ _Float16 Wb[3][4096];   // 24 KB
  const int tid = threadIdx.x;
  const int lane = tid & 63;
  const int wv = tid >> 6;           // 2 waves: col half

  // XCD-chunked bijective swizzle (2000 = 8*250); 4 col-blocks adjacent.
  const int l = blockIdx.x;
  const int lp = (l & 7) * 250 + (l >> 3);
  const int row0 = (lp >> 2) * BM;
  const int c0 = (lp & 3) * BN;

  // per-lane DMA source bases: chunk j covers rows/cols (4wv+j)*16 + (lane&15),
  // k-slice (lane>>4)*8. LDS dest is wave-uniform; HW writes base + lane*16.
  const int lsub = (lane & 15), ksl = (lane >> 4) * 8;
  const _Float16* aA0 = Af + (size_t)(row0 + (4 * wv + 0) * 16 + lsub) * ENC2n + ksl;
  const _Float16* aA1 = Af + (size_t)(row0 + (4 * wv + 1) * 16 + lsub) * ENC2n + ksl;
  const _Float16* aA2 = Af + (size_t)(row0 + (4 * wv + 2) * 16 + lsub) * ENC2n + ksl;
  const _Float16* aA3 = Af + (size_t)(row0 + (4 * wv + 3) * 16 + lsub) * ENC2n + ksl;
  const _Float16* aW0 = Wt + (size_t)(c0 + (4 * wv + 0) * 16 + lsub) * ENC2n + ksl;
  const _Float16* aW1 = Wt + (size_t)(c0 + (4 * wv + 1) * 16 + lsub) * ENC2n + ksl;
  const _Float16* aW2 = Wt + (size_t)(c0 + (4 * wv + 2) * 16 + lsub) * ENC2n + ksl;
  const _Float16* aW3 = Wt + (size_t)(c0 + (4 * wv + 3) * 16 + lsub) * ENC2n + ksl;

  f32x4 acc[8][4];
#pragma unroll
  for (int m = 0; m < 8; ++m)
#pragma unroll
    for (int n = 0; n < 4; ++n) acc[m][n] = (f32x4)0.f;

  // ---- prologue: tiles 0,1 in flight (16/wave); force tile 0 ----
  DMAW(0, 0); DMAA(0, 0);
  DMAW(1, 1); DMAA(1, 1);
  BARN(8);

  // ---- 30 steady phases: issue tile t+2 -> buf (t+2)%3; compute t ----
  for (int t3 = 0; t3 < 30; t3 += 3) {
    DMAW(2, t3 + 2); DMAA(2, t3 + 2); COMPUTE(0); BARN(8);
    DMAW(0, t3 + 3); DMAA(0, t3 + 3); COMPUTE(1); BARN(8);
    DMAW(1, t3 + 4); DMAA(1, t3 + 4); COMPUTE(2); BARN(8);
  }
  // tail: tile 30 (buf 0) forced by last BARN(8); tile 31 (buf 1) by BARN(0)
  COMPUTE(0);
  BARN(0);
  COMPUTE(1);

  // ---- epilogue ----
  __syncthreads();
  float* tcs = (float*)&Ab[0][0];        // reuse LDS: tmpconv slice [128][10]
  {
    const float* __restrict__ tsrc = ws + (size_t)row0 * NKn;
    for (int i = tid; i < BM * NKn; i += 128) tcs[i] = tsrc[i];
  }
  __syncthreads();

  const float* __restrict__ DB = ws + OFF_DB;
  const int lr = lane & 15, lg = lane >> 4;
  float wc2[4][NKn], wsc[4];
  int cl[4];
#pragma unroll
  for (int fn = 0; fn < 4; ++fn) {
    cl[fn] = c0 + wv * 64 + fn * 16 + lr;
    wsc[fn] = wscore[cl[fn]];
#pragma unroll
    for (int k = 0; k < NKn; ++k) wc2[fn][k] = Wc2s[k * ATTNn + cl[fn]];
  }

#pragma unroll
  for (int fm = 0; fm < 8; ++fm) {
#pragma unroll
    for (int r = 0; r < 4; ++r) {
      const int rowL = fm * 16 + lg * 4 + r;
      const int grow = row0 + rowL;
      const int b = grow / Tn;
      const float* __restrict__ tk = &tcs[rowL * NKn];
      float tkv[NKn];
#pragma unroll
      for (int k = 0; k < NKn; ++k) tkv[k] = tk[k];
      float p = 0.f;
#pragma unroll
      for (int fn = 0; fn < 4; ++fn) {
        float v = acc[fm][fn][r] + DB[b * ATTNn + cl[fn]];
#pragma unroll
        for (int k = 0; k < NKn; ++k) v = fmaf(tkv[k], wc2[fn][k], v);
        p = fmaf(wsc[fn], fast_tanh(v), p);
      }
      p += __shfl_down(p, 8, 16);
      p += __shfl_down(p, 4, 16);
      p += __shfl_down(p, 2, 16);
      p += __shfl_down(p, 1, 16);
      if (lr == 0) atomicAdd(&ws[OFF_SCORE + grow], p);
    }
  }
}

// ---------------------------------------------------------------------------
// k_softmax: masked softmax over T per batch row
// ---------------------------------------------------------------------------
__global__ __launch_bounds__(256) void k_softmax(const float* __restrict__ ws,
                                                 const float* __restrict__ mask,
                                                 float* __restrict__ out) {
  const int b = blockIdx.x, tid = threadIdx.x;
  const float* __restrict__ s = ws + OFF_SCORE + b * Tn;
  const float* __restrict__ mrow = mask + b * Tn;
  float* __restrict__ orow = out + b * Tn;
  __shared__ float red[4];

  float m = -1e30f;
  for (int t = tid; t < Tn; t += 256) m = fmaxf(m, s[t]);
#pragma unroll
  for (int off = 32; off; off >>= 1) m = fmaxf(m, __shfl_down(m, off));
  if ((tid & 63) == 0) red[tid >> 6] = m;
  __syncthreads();
  m = fmaxf(fmaxf(red[0], red[1]), fmaxf(red[2], red[3]));
  __syncthreads();

  float sum = 0.f;
  for (int t = tid; t < Tn; t += 256) {
    const float e = expf(s[t] - m) * mrow[t];
    orow[t] = e;
    sum += e;
  }
#pragma unroll
  for (int off = 32; off; off >>= 1) sum += __shfl_down(sum, off);
  if ((tid & 63) == 0) red[tid >> 6] = sum;
  __syncthreads();
  sum = red[0] + red[1] + red[2] + red[3];
  const float inv = 1.f / sum;
  for (int t = tid; t < Tn; t += 256) orow[t] *= inv;
}

// ---------------------------------------------------------------------------
extern "C" void kernel_launch(void* const* d_in, const int* in_sizes, int n_in,
                              void* d_out, int out_size, void* d_ws, size_t ws_size,
                              hipStream_t stream) {
  const float* enc   = (const float*)d_in[0];
  const float* hid   = (const float*)d_in[1];
  const float* alpha = (const float*)d_in[2];
  const float* mask  = (const float*)d_in[3];
  const float* Wconv = (const float*)d_in[4];
  const float* Wc2s  = (const float*)d_in[5];
  const float* Wenc  = (const float*)d_in[6];
  const float* benc  = (const float*)d_in[7];
  const float* Wdec  = (const float*)d_in[8];
  const float* wscr  = (const float*)d_in[9];
  float* out = (float*)d_out;
  float* ws  = (float*)d_ws;
  _Float16* Wt = (_Float16*)(ws + OFF_WT);
  _Float16* Af = (_Float16*)(ws + OFF_AF16);

  k_wt<<<dim3(ENC2n / 32, ATTNn / 32), 256, 0, stream>>>(Wenc, Wt);
  k_conv<<<dim3((Tn + 255) / 256, Bn), 256, 0, stream>>>(alpha, Wconv, ws);
  k_dec<<<Bn, DECn, 0, stream>>>(hid, Wdec, benc, ws);
  k_acvt<<<4096, 256, 0, stream>>>(enc, Af);
  k_main<<<2000, 128, 0, stream>>>(Af, Wt, Wc2s, wscr, ws);
  k_softmax<<<Bn, 256, 0, stream>>>(ws, mask, out);
}

// Round 11
// 261.048 us; speedup vs baseline: 1.2528x; 1.2528x over previous
//
#include <hip/hip_runtime.h>
#include <math.h>

// Problem constants
#define Bn    32
#define Tn    2000
#define Mrows (Bn * Tn)        // 64000
#define ENC2n 1024
#define ATTNn 512
#define DECn  512
#define NKn   10
#define KWn   100
#define PADn  50

// workspace layout (floats):
//   [0, 640000)            tmpconv [64000][10]
//   [OFF_DB, +16384)       DB[32][512] = b_enc + dec_e
//   [OFF_SCORE, +64000)    score [64000]
//   [OFF_WT, +262144)      Wt f16 [512 col][1024 k]  (transposed W_enc)
#define OFF_DB    (Mrows * NKn)
#define OFF_SCORE (OFF_DB + Bn * ATTNn)
#define OFF_WT    (OFF_SCORE + Mrows)

typedef _Float16 v8h __attribute__((ext_vector_type(8)));
typedef float f32x4 __attribute__((ext_vector_type(4)));

__device__ __forceinline__ float fast_tanh(float v) {
  const float e = __expf(2.f * v);
  return 1.f - 2.f * __builtin_amdgcn_rcpf(e + 1.f);
}

__device__ __forceinline__ void gload_lds16(const void* g, void* l) {
  __builtin_amdgcn_global_load_lds(
      (const __attribute__((address_space(1))) void*)g,
      (__attribute__((address_space(3))) void*)l, 16, 0, 0);
}

// ---------------------------------------------------------------------------
// k_wt: W_enc [1024][512] f32 -> Wt [512][1024] f16 (transpose + convert, RNE)
// ---------------------------------------------------------------------------
__global__ __launch_bounds__(256) void k_wt(const float* __restrict__ W,
                                            _Float16* __restrict__ Wt) {
  __shared__ float sh[32][33];
  const int x = threadIdx.x & 31, y = threadIdx.x >> 5;  // y: 0..7
  const int k0 = blockIdx.x * 32, c0 = blockIdx.y * 32;
  for (int i = y; i < 32; i += 8) sh[i][x] = W[(size_t)(k0 + i) * ATTNn + c0 + x];
  __syncthreads();
  for (int i = y; i < 32; i += 8)
    Wt[(size_t)(c0 + i) * ENC2n + k0 + x] = (_Float16)sh[x][i];
}

// ---------------------------------------------------------------------------
// k_conv: tmpconv[b,t,k] = sum_i alpha[b,t+i-50]*Wconv[k,i]; zero score acc
// ---------------------------------------------------------------------------
__global__ __launch_bounds__(256) void k_conv(const float* __restrict__ alpha,
                                              const float* __restrict__ Wconv,
                                              float* __restrict__ ws) {
  __shared__ float sh[256 + KWn - 1];
  __shared__ float wc[NKn * KWn];
  const int b = blockIdx.y;
  const int t0 = blockIdx.x * 256;
  const int tid = threadIdx.x;

  for (int i = tid; i < NKn * KWn; i += 256) wc[i] = Wconv[i];
  const float* __restrict__ arow = alpha + b * Tn;
  for (int i = tid; i < 256 + KWn - 1; i += 256) {
    const int t = t0 - PADn + i;
    sh[i] = (t >= 0 && t < Tn) ? arow[t] : 0.f;
  }
  __syncthreads();

  const int t = t0 + tid;
  if (t < Tn) {
    float acc[NKn];
#pragma unroll
    for (int k = 0; k < NKn; ++k) acc[k] = 0.f;
    for (int i = 0; i < KWn; ++i) {
      const float a = sh[tid + i];
#pragma unroll
      for (int k = 0; k < NKn; ++k) acc[k] = fmaf(a, wc[k * KWn + i], acc[k]);
    }
    float* tp = ws + (size_t)(b * Tn + t) * NKn;
#pragma unroll
    for (int k = 0; k < NKn; ++k) tp[k] = acc[k];
    ws[OFF_SCORE + b * Tn + t] = 0.f;
  }
}

// ---------------------------------------------------------------------------
// k_dec: DB[b,a] = b_enc[a] + sum_d h[b,d]*Wdec[d,a]
// ---------------------------------------------------------------------------
__global__ __launch_bounds__(512) void k_dec(const float* __restrict__ h,
                                             const float* __restrict__ Wdec,
                                             const float* __restrict__ benc,
                                             float* __restrict__ ws) {
  __shared__ float sh[DECn];
  const int b = blockIdx.x;
  const int a = threadIdx.x;
  sh[a] = h[b * DECn + a];
  __syncthreads();
  float acc = 0.f;
  for (int d = 0; d < DECn; ++d) acc = fmaf(sh[d], Wdec[d * ATTNn + a], acc);
  ws[OFF_DB + b * ATTNn + a] = benc[a] + acc;
}

#define BM 128
#define BN 128
#define BK 32
#define NT (ENC2n / BK)   // 32

// ---------------------------------------------------------------------------
// k_main: 128x128, BK=32, 4 waves. Tile = 512 16B-units u = row*4 + g;
// LDS slot s = u ^ ((u>>2)&7) -> frag reads (16 lanes, same g, rows m*16+lr)
// become 2-way (free) instead of 8-way. A: reg-staged 2-deep from f32
// (coalesced 64B/thread), RNE cvt, ds_write to swizzled slot. W: DMA
// (global_load_lds) reading a CONTIGUOUS 1KB whose per-lane 16B source is
// inverse-swizzle-permuted within the window (coalescing preserved); linear
// LDS dest. Steady phase p: LOADA(p+2)+DMAW(p+2) | COMPUTE(p) | vmcnt(6)
// (forces A(p+1)+W(p+1)) | CVTSTORE(p+1) | vmcnt(6)+lgkmcnt(0)+s_barrier.
// LDS = Ab[2]+Wb[3] = 40 KB.
// ---------------------------------------------------------------------------
#define LOADA(P, kt)                                  \
  (P##0) = *(const float4*)(asrc + (kt) * BK);        \
  (P##1) = *(const float4*)(asrc + (kt) * BK + 4);    \
  (P##2) = *(const float4*)(asrc + (kt) * BK + 8);    \
  (P##3) = *(const float4*)(asrc + (kt) * BK + 12);

#define CVTSTORE(P, ab) {                                                    \
  v8h h0, h1;                                                                \
  h0[0] = (_Float16)(P##0).x; h0[1] = (_Float16)(P##0).y;                    \
  h0[2] = (_Float16)(P##0).z; h0[3] = (_Float16)(P##0).w;                    \
  h0[4] = (_Float16)(P##1).x; h0[5] = (_Float16)(P##1).y;                    \
  h0[6] = (_Float16)(P##1).z; h0[7] = (_Float16)(P##1).w;                    \
  h1[0] = (_Float16)(P##2).x; h1[1] = (_Float16)(P##2).y;                    \
  h1[2] = (_Float16)(P##2).z; h1[3] = (_Float16)(P##2).w;                    \
  h1[4] = (_Float16)(P##3).x; h1[5] = (_Float16)(P##3).y;                    \
  h1[6] = (_Float16)(P##3).z; h1[7] = (_Float16)(P##3).w;                    \
  *(v8h*)&Ab[ab][sw0] = h0;                                                  \
  *(v8h*)&Ab[ab][sw1] = h1; }

#define DMAW(wb, kt) {                                                       \
  gload_lds16(wp0 + (kt) * BK, &Wb[wb][(wv * 2) * 512]);                     \
  gload_lds16(wp1 + (kt) * BK, &Wb[wb][(wv * 2 + 1) * 512]); }

#define COMPUTE(ab, wb) {                                                    \
  v8h af[4], bf[4];                                                          \
  _Pragma("unroll")                                                          \
  for (int m = 0; m < 4; ++m)                                                \
    af[m] = *(const v8h*)&Ab[ab][wm * 2048 + m * 512 + aoff];                \
  _Pragma("unroll")                                                          \
  for (int n = 0; n < 4; ++n)                                                \
    bf[n] = *(const v8h*)&Wb[wb][wn * 2048 + n * 512 + aoff];                \
  __builtin_amdgcn_s_setprio(1);                                             \
  _Pragma("unroll")                                                          \
  for (int m = 0; m < 4; ++m)                                                \
    _Pragma("unroll")                                                        \
    for (int n = 0; n < 4; ++n)                                              \
      acc[m][n] = __builtin_amdgcn_mfma_f32_16x16x32_f16(af[m], bf[n],       \
                                                         acc[m][n], 0, 0, 0);\
  __builtin_amdgcn_s_setprio(0); }

#define VMC(N) asm volatile("s_waitcnt vmcnt(" #N ")" ::: "memory");

#define BARN(N) {                                                            \
  asm volatile("s_waitcnt vmcnt(" #N ") lgkmcnt(0)" ::: "memory");           \
  __builtin_amdgcn_s_barrier(); }

#define PHASE(ab, wc, wd, Pl, Pc, kt) {                                      \
  LOADA(Pl, kt);                                                             \
  DMAW(wd, kt);                                                              \
  __builtin_amdgcn_sched_barrier(0);                                         \
  COMPUTE(ab, wc);                                                           \
  VMC(6);                                                                    \
  CVTSTORE(Pc, (ab) ^ 1);                                                    \
  BARN(6); }

__global__ __launch_bounds__(256, 3) void k_main(
    const float* __restrict__ A,        // [64000][1024] f32
    const _Float16* __restrict__ Wt,    // [512][1024] f16
    const float* __restrict__ Wc2s,     // [10][512]
    const float* __restrict__ wscore,   // [512]
    float* __restrict__ ws) {
  __shared__ _Float16 Ab[2][4096];   // 16 KB
  __shared__ _Float16 Wb[3][4096];   // 24 KB
  const int tid = threadIdx.x;
  const int lane = tid & 63;
  const int wv = tid >> 6;
  const int wm = wv >> 1, wn = wv & 1;

  // XCD-chunked bijective swizzle (2000 = 8*250); 4 col-blocks adjacent.
  const int l = blockIdx.x;
  const int lp = (l & 7) * 250 + (l >> 3);
  const int row0 = (lp >> 2) * BM;
  const int c0 = (lp & 3) * BN;

  // A staging: thread -> row sr = tid>>1, k-half hh = tid&1 (16 f32 = 64B,
  // coalesced). Data units u0 = sr*4 + hh*2, u0+1; swizzled slots (f16 idx).
  const int sr = tid >> 1, hh = tid & 1, mm = sr & 7;
  const int u0 = sr * 4 + hh * 2;
  const int sw0 = (u0 ^ mm) * 8;
  const int sw1 = ((u0 + 1) ^ mm) * 8;
  const float* __restrict__ asrc =
      A + (size_t)(row0 + sr) * ENC2n + hh * 16;

  // Swizzled fragment-read offset (f16 idx), same for A and W:
  // unit u = (16m + lr)*4 + g, slot = u ^ (lr&7); lr = lane&15, g = lane>>4.
  const int aoff = ((((lane & 15) << 2) | (lane >> 4)) ^ (lane & 7)) * 8;

  // W DMA per-lane source: LDS slot s = (wv*2+j)*64 + lane holds data unit
  // u = inv(s): row = ((s>>3)<<1)|(s2^s4); g = ((s1^s3)<<1)|(s0^s2^s4).
  const _Float16* wp0;
  const _Float16* wp1;
  {
    const int s0i = (wv * 2) * 64 + lane;
    const int s1i = s0i + 64;
    int s = s0i;
    int rw = ((s >> 3) << 1) | (((s >> 2) ^ (s >> 4)) & 1);
    int gg = ((((s >> 1) ^ (s >> 3)) & 1) << 1) | ((s ^ (s >> 2) ^ (s >> 4)) & 1);
    wp0 = Wt + (size_t)(c0 + rw) * ENC2n + gg * 8;
    s = s1i;
    rw = ((s >> 3) << 1) | (((s >> 2) ^ (s >> 4)) & 1);
    gg = ((((s >> 1) ^ (s >> 3)) & 1) << 1) | ((s ^ (s >> 2) ^ (s >> 4)) & 1);
    wp1 = Wt + (size_t)(c0 + rw) * ENC2n + gg * 8;
  }

  f32x4 acc[4][4];
#pragma unroll
  for (int m = 0; m < 4; ++m)
#pragma unroll
    for (int n = 0; n < 4; ++n) acc[m][n] = (f32x4)0.f;

  float4 X0, X1, X2, X3, Y0, Y1, Y2, Y3;

  // ---- prologue: A0->X, W0->Wb0, A1->Y, W1->Wb1; A0 -> Ab0 ----
  LOADA(X, 0);
  DMAW(0, 0);
  LOADA(Y, 1);
  DMAW(1, 1);
  VMC(8);             // forces A0 (12 -> 8)
  CVTSTORE(X, 0);
  BARN(6);            // forces W0; leaves A1(4)+W1(2)=6

  // ---- 30 steady phases (p = 0..29), period 6 ----
  for (int it = 0; it < 5; ++it) {
    const int k2 = it * 6 + 2;
    PHASE(0, 0, 2, X, Y, k2 + 0);
    PHASE(1, 1, 0, Y, X, k2 + 1);
    PHASE(0, 2, 1, X, Y, k2 + 2);
    PHASE(1, 0, 2, Y, X, k2 + 3);
    PHASE(0, 1, 0, X, Y, k2 + 4);
    PHASE(1, 2, 1, Y, X, k2 + 5);
  }
  // tail: p=30 computes tile 30 (Ab0, Wb0); cvt A31 (Y) -> Ab1; p=31.
  COMPUTE(0, 0);
  VMC(0);
  CVTSTORE(Y, 1);
  BARN(0);
  COMPUTE(1, 1);

  // ---- epilogue ----
  __syncthreads();
  float* tcs = (float*)&Ab[0][0];        // reuse LDS: tmpconv slice [128][10]
  {
    const float* __restrict__ tsrc = ws + (size_t)row0 * NKn;
    for (int i = tid; i < BM * NKn; i += 256) tcs[i] = tsrc[i];
  }
  __syncthreads();

  const float* __restrict__ DB = ws + OFF_DB;
  const int lr = lane & 15, lg = lane >> 4;
  float wc2[4][NKn], wsc[4];
  int cl[4];
#pragma unroll
  for (int fn = 0; fn < 4; ++fn) {
    cl[fn] = c0 + wn * 64 + fn * 16 + lr;
    wsc[fn] = wscore[cl[fn]];
#pragma unroll
    for (int k = 0; k < NKn; ++k) wc2[fn][k] = Wc2s[k * ATTNn + cl[fn]];
  }

#pragma unroll
  for (int fm = 0; fm < 4; ++fm) {
#pragma unroll
    for (int r = 0; r < 4; ++r) {
      const int rowL = wm * 64 + fm * 16 + lg * 4 + r;
      const int grow = row0 + rowL;
      const int b = grow / Tn;
      const float* __restrict__ tk = &tcs[rowL * NKn];
      float tkv[NKn];
#pragma unroll
      for (int k = 0; k < NKn; ++k) tkv[k] = tk[k];
      float p = 0.f;
#pragma unroll
      for (int fn = 0; fn < 4; ++fn) {
        float v = acc[fm][fn][r] + DB[b * ATTNn + cl[fn]];
#pragma unroll
        for (int k = 0; k < NKn; ++k) v = fmaf(tkv[k], wc2[fn][k], v);
        p = fmaf(wsc[fn], fast_tanh(v), p);
      }
      p += __shfl_down(p, 8, 16);
      p += __shfl_down(p, 4, 16);
      p += __shfl_down(p, 2, 16);
      p += __shfl_down(p, 1, 16);
      if (lr == 0) atomicAdd(&ws[OFF_SCORE + grow], p);
    }
  }
}

// ---------------------------------------------------------------------------
// k_softmax: masked softmax over T per batch row
// ---------------------------------------------------------------------------
__global__ __launch_bounds__(256) void k_softmax(const float* __restrict__ ws,
                                                 const float* __restrict__ mask,
                                                 float* __restrict__ out) {
  const int b = blockIdx.x, tid = threadIdx.x;
  const float* __restrict__ s = ws + OFF_SCORE + b * Tn;
  const float* __restrict__ mrow = mask + b * Tn;
  float* __restrict__ orow = out + b * Tn;
  __shared__ float red[4];

  float m = -1e30f;
  for (int t = tid; t < Tn; t += 256) m = fmaxf(m, s[t]);
#pragma unroll
  for (int off = 32; off; off >>= 1) m = fmaxf(m, __shfl_down(m, off));
  if ((tid & 63) == 0) red[tid >> 6] = m;
  __syncthreads();
  m = fmaxf(fmaxf(red[0], red[1]), fmaxf(red[2], red[3]));
  __syncthreads();

  float sum = 0.f;
  for (int t = tid; t < Tn; t += 256) {
    const float e = expf(s[t] - m) * mrow[t];
    orow[t] = e;
    sum += e;
  }
#pragma unroll
  for (int off = 32; off; off >>= 1) sum += __shfl_down(sum, off);
  if ((tid & 63) == 0) red[tid >> 6] = sum;
  __syncthreads();
  sum = red[0] + red[1] + red[2] + red[3];
  const float inv = 1.f / sum;
  for (int t = tid; t < Tn; t += 256) orow[t] *= inv;
}

// ---------------------------------------------------------------------------
extern "C" void kernel_launch(void* const* d_in, const int* in_sizes, int n_in,
                              void* d_out, int out_size, void* d_ws, size_t ws_size,
                              hipStream_t stream) {
  const float* enc   = (const float*)d_in[0];
  const float* hid   = (const float*)d_in[1];
  const float* alpha = (const float*)d_in[2];
  const float* mask  = (const float*)d_in[3];
  const float* Wconv = (const float*)d_in[4];
  const float* Wc2s  = (const float*)d_in[5];
  const float* Wenc  = (const float*)d_in[6];
  const float* benc  = (const float*)d_in[7];
  const float* Wdec  = (const float*)d_in[8];
  const float* wscr  = (const float*)d_in[9];
  float* out = (float*)d_out;
  float* ws  = (float*)d_ws;
  _Float16* Wt = (_Float16*)(ws + OFF_WT);

  k_wt<<<dim3(ENC2n / 32, ATTNn / 32), 256, 0, stream>>>(Wenc, Wt);
  k_conv<<<dim3((Tn + 255) / 256, Bn), 256, 0, stream>>>(alpha, Wconv, ws);
  k_dec<<<Bn, DECn, 0, stream>>>(hid, Wdec, benc, ws);
  k_main<<<2000, 256, 0, stream>>>(enc, Wt, Wc2s, wscr, ws);
  k_softmax<<<Bn, 256, 0, stream>>>(ws, mask, out);
}